// Round 10
// baseline (555.225 us; speedup 1.0000x reference)
//
#include <hip/hip_runtime.h>
#include <math.h>

#define DDIM 16
#define NSTEPS 64
#define BATCH_N 2097152L   // fixed problem size: 2^21 rows (do NOT trust in_sizes units)
#define TABN 8192          // GELU table entries, u in [-16,16], h = 1/256
#define TILES 8            // row-tiles per wave
#define ROWS_PER_WAVE (16 * TILES)        // 128
#define ROWS_PER_BLOCK (4 * ROWS_PER_WAVE) // 512 (4 waves)

typedef _Float16 half4   __attribute__((ext_vector_type(4)));
typedef __fp16   fp16x2  __attribute__((ext_vector_type(2)));  // cvt_pkrtz return type
typedef float    floatx4 __attribute__((ext_vector_type(4)));

// Packed per-lane MFMA A-operand fragments for W^T and (V^T * 1/N), f16,
// plus the exact-erf GELU lookup table G(u) in f16 (g = G(u), scale 1/N in V).
__device__ half4    g_pw[NSTEPS * 64];
__device__ half4    g_pv[NSTEPS * 64];
__device__ _Float16 g_tab[TABN];

__global__ __launch_bounds__(256) void pack_wv(const float* __restrict__ W,
                                               const float* __restrict__ V)
{
    int t = blockIdx.x * 256 + threadIdx.x;   // 0..4095 = 64 steps * 64 lanes
    int L = t & 63;
    int s = t >> 6;
    int q = L >> 4, r = L & 15;
    const float vscale = 1.0f / (float)NSTEPS;
    const float* Ws = W + s * DDIM * DDIM;
    const float* Vs = V + s * DDIM * DDIM;
    half4 w, v;
    #pragma unroll
    for (int j = 0; j < 4; ++j) {
        w[j] = (_Float16)Ws[(4 * q + j) * DDIM + r];
        v[j] = (_Float16)(Vs[(4 * q + j) * DDIM + r] * vscale);
    }
    g_pw[t] = w;
    g_pv[t] = v;

    // GELU table: entry k <-> u_k = (k-4096)/256; value = exact-erf GELU(u_k),
    // f16 round-to-nearest storage.
    #pragma unroll
    for (int e = 0; e < 2; ++e) {
        int   k  = 2 * t + e;
        float u  = ((float)k - 4096.0f) * (1.0f / 256.0f);
        float gg = 0.5f * u * (1.0f + erff(u * 0.70710678f));
        g_tab[k] = (_Float16)gg;
    }
}

// ---------------------------------------------------------------------------
// R10 = R9 with the OOB rowbase bug fixed.
// R9's crash: rowbase stride evaluated to 2048 rows/block against a grid
// sized for 512 -> 4x OOB. Now explicit: block covers 512 rows, wave 128.
// Static check: max row = 4095*512 + 3*128 + 7*16 + 15 = 2097151 = BATCH-1. OK
//
// Theory under test (from R8 accounting): MFMA 27%, VALU ~38%, LDS ~23% ->
// no pipe saturated; kernel is dependency-latency-bound (cvt -> MFMA -> idx
// -> ds gather ~120cy -> MFMA) with too few independent chains.
//  1. TILES 4 -> 8: 2x independent chains/wave, half the waves.
//     __launch_bounds__(256,6): VGPR cap ~85, h[8]+frags fit, no spill.
//  2. Index math 5 -> 3 ops: off = ((int)fma(u,512,8193)) & 16382
//     (floor(2y)&~1 == 2*floor(y): bit-identical to R8 rounding; '&' bounds
//     the read for ANY bit pattern -> crash-safe; med3 dropped, |u|>15.99
//     is a ~16-sigma event, max observed ~6.5 sigma).
// ---------------------------------------------------------------------------
__global__ __launch_bounds__(256, 6) void resnet_mfma_kernel(
    const float* __restrict__ x,
    float* __restrict__ out)
{
    __shared__ _Float16 tab[TABN];   // 16 KB

    const int tid = threadIdx.x;

    // Block-copy table global -> LDS: 16384 B / (256 thr * 16 B) = 4 float4s.
    {
        const float4* src = reinterpret_cast<const float4*>(g_tab);
        float4*       dst = reinterpret_cast<float4*>(tab);
        #pragma unroll
        for (int k = 0; k < 4; ++k)
            dst[tid + 256 * k] = src[tid + 256 * k];
    }

    const int lane = tid & 63;
    const int wave = tid >> 6;
    const int q = lane >> 4, r = lane & 15;

    const long rowbase = (long)blockIdx.x * ROWS_PER_BLOCK
                       + (long)wave * ROWS_PER_WAVE;

    floatx4 h[TILES];
    #pragma unroll
    for (int t = 0; t < TILES; ++t) {
        const float4* p = reinterpret_cast<const float4*>(
            x + (rowbase + t * 16 + r) * DDIM + 4 * q);
        float4 v = *p;
        h[t][0] = v.x; h[t][1] = v.y; h[t][2] = v.z; h[t][3] = v.w;
    }

    half4 wf = g_pw[lane];
    half4 vf = g_pv[lane];

    const char* tabb = reinterpret_cast<const char*>(tab);

    __syncthreads();   // table ready

    for (int s = 0; s < NSTEPS; ++s) {
        int sn = (s < NSTEPS - 1) ? s + 1 : s;
        half4 wfn = g_pw[sn * 64 + lane];
        half4 vfn = g_pv[sn * 64 + lane];

        // Phase 1: h (fp32, C/D layout) -> f16 B-operand, all tiles.
        union { fp16x2 h2[2]; half4 h4; } hb[TILES];
        #pragma unroll
        for (int t = 0; t < TILES; ++t) {
            hb[t].h2[0] = __builtin_amdgcn_cvt_pkrtz(h[t][0], h[t][1]);
            hb[t].h2[1] = __builtin_amdgcn_cvt_pkrtz(h[t][2], h[t][3]);
        }

        // Phase 2: u = W^T @ h^T, all tiles (independent MFMAs).
        floatx4 u[TILES];
        #pragma unroll
        for (int t = 0; t < TILES; ++t) {
            floatx4 zero = {0.f, 0.f, 0.f, 0.f};
            u[t] = __builtin_amdgcn_mfma_f32_16x16x16f16(wf, hb[t].h4, zero, 0, 0, 0);
        }

        // Phase 3: g = G_table(u): 3 VALU (fma, cvt, and) + ds_read_u16 per elem.
        half4 gb[TILES];
        #pragma unroll
        for (int t = 0; t < TILES; ++t) {
            half4 g4;
            #pragma unroll
            for (int j = 0; j < 4; ++j) {
                int off = ((int)fmaf(u[t][j], 512.0f, 8193.0f)) & 16382;
                g4[j] = *reinterpret_cast<const _Float16*>(tabb + off);
            }
            gb[t] = g4;
        }

        // Phase 4: h += g @ (V/N), all tiles (residual in MFMA C operand).
        #pragma unroll
        for (int t = 0; t < TILES; ++t) {
            h[t] = __builtin_amdgcn_mfma_f32_16x16x16f16(vf, gb[t], h[t], 0, 0, 0);
        }

        wf = wfn; vf = vfn;
    }

    #pragma unroll
    for (int t = 0; t < TILES; ++t) {
        float4 v = make_float4(h[t][0], h[t][1], h[t][2], h[t][3]);
        *reinterpret_cast<float4*>(out + (rowbase + t * 16 + r) * DDIM + 4 * q) = v;
    }
}

extern "C" void kernel_launch(void* const* d_in, const int* in_sizes, int n_in,
                              void* d_out, int out_size, void* d_ws, size_t ws_size,
                              hipStream_t stream) {
    (void)in_sizes; (void)n_in; (void)out_size; (void)d_ws; (void)ws_size;

    const float* x = (const float*)d_in[0];   // [2^21, 16] fp32
    const float* W = (const float*)d_in[1];   // [64, 16, 16] fp32
    const float* V = (const float*)d_in[2];   // [64, 16, 16] fp32
    float* out = (float*)d_out;

    pack_wv<<<16, 256, 0, stream>>>(W, V);

    // 512 rows per block (4 waves x 8 tiles x 16 rows); grid = 2^21/512 = 4096.
    resnet_mfma_kernel<<<(int)(BATCH_N / ROWS_PER_BLOCK), 256, 0, stream>>>(x, out);
}

// Round 11
// 538.406 us; speedup vs baseline: 1.0312x; 1.0312x over previous
//
#include <hip/hip_runtime.h>
#include <math.h>

#define DDIM 16
#define NSTEPS 64
#define BATCH_N 2097152L   // fixed problem size: 2^21 rows (do NOT trust in_sizes units)
#define TABN 8192          // GELU table entries, u in [-16,16], h = 1/256
#define TILES 8            // row-tiles per wave
#define ROWS_PER_WAVE (16 * TILES)         // 128
#define ROWS_PER_BLOCK (4 * ROWS_PER_WAVE) // 512 (4 waves)

typedef _Float16 half4   __attribute__((ext_vector_type(4)));
typedef __fp16   fp16x2  __attribute__((ext_vector_type(2)));  // cvt_pkrtz return type
typedef float    floatx4 __attribute__((ext_vector_type(4)));

// Packed per-lane MFMA A-operand fragments for W^T and (V^T * 1/N), f16,
// plus the exact-erf GELU lookup table G(u) in f16 (g = G(u), scale 1/N in V).
__device__ half4    g_pw[NSTEPS * 64];
__device__ half4    g_pv[NSTEPS * 64];
__device__ _Float16 g_tab[TABN];

__global__ __launch_bounds__(256) void pack_wv(const float* __restrict__ W,
                                               const float* __restrict__ V)
{
    int t = blockIdx.x * 256 + threadIdx.x;   // 0..4095 = 64 steps * 64 lanes
    int L = t & 63;
    int s = t >> 6;
    int q = L >> 4, r = L & 15;
    const float vscale = 1.0f / (float)NSTEPS;
    const float* Ws = W + s * DDIM * DDIM;
    const float* Vs = V + s * DDIM * DDIM;
    half4 w, v;
    #pragma unroll
    for (int j = 0; j < 4; ++j) {
        w[j] = (_Float16)Ws[(4 * q + j) * DDIM + r];
        v[j] = (_Float16)(Vs[(4 * q + j) * DDIM + r] * vscale);
    }
    g_pw[t] = w;
    g_pv[t] = v;

    // GELU table: entry k <-> u_k = (k-4096)/256; value = exact-erf GELU(u_k),
    // f16 round-to-nearest storage.
    #pragma unroll
    for (int e = 0; e < 2; ++e) {
        int   k  = 2 * t + e;
        float u  = ((float)k - 4096.0f) * (1.0f / 256.0f);
        float gg = 0.5f * u * (1.0f + erff(u * 0.70710678f));
        g_tab[k] = (_Float16)gg;
    }
}

// ---------------------------------------------------------------------------
// R11: pipe rebalance. R10's null result (TILES 4->8: 455->453us, conflicts
// IDENTICAL 1.551e8) proves the CU-shared LDS pipe is the saturated resource:
// per CU, gather base + 6.1e5 conflict-cy ~= the whole 1.09e6-cy kernel.
// Trans pipe 0%, HBM 2.7%, VALU ~25% (time-based) -> offload 1/4 of GELU
// elements (j=3 of each tile) to the trans pipe via the R3-validated f32
// exp2-sigmoid (per-element independent: no R4 serial chain, no R5 f16-z).
// Expected: LDS load x0.75 (~270us-equiv) vs SIMD VALU+trans (~260us-equiv).
// ---------------------------------------------------------------------------
__global__ __launch_bounds__(256, 6) void resnet_mfma_kernel(
    const float* __restrict__ x,
    float* __restrict__ out)
{
    __shared__ _Float16 tab[TABN];   // 16 KB

    const int tid = threadIdx.x;

    // Block-copy table global -> LDS: 16384 B / (256 thr * 16 B) = 4 float4s.
    {
        const float4* src = reinterpret_cast<const float4*>(g_tab);
        float4*       dst = reinterpret_cast<float4*>(tab);
        #pragma unroll
        for (int k = 0; k < 4; ++k)
            dst[tid + 256 * k] = src[tid + 256 * k];
    }

    const int lane = tid & 63;
    const int wave = tid >> 6;
    const int q = lane >> 4, r = lane & 15;

    const long rowbase = (long)blockIdx.x * ROWS_PER_BLOCK
                       + (long)wave * ROWS_PER_WAVE;
    // Static bound check: max row = 4095*512 + 3*128 + 7*16 + 15 = 2097151. OK

    floatx4 h[TILES];
    #pragma unroll
    for (int t = 0; t < TILES; ++t) {
        const float4* p = reinterpret_cast<const float4*>(
            x + (rowbase + t * 16 + r) * DDIM + 4 * q);
        float4 v = *p;
        h[t][0] = v.x; h[t][1] = v.y; h[t][2] = v.z; h[t][3] = v.w;
    }

    // tanh-GELU sigmoid form for the trans-path element:
    // g = u - u/(1+2^z), z = u * fma(Kc1, u^2, K)   (R3-validated)
    const float K   = 2.3022082f;
    const float Kc1 = 0.10294340f;   // K * 0.044715

    half4 wf = g_pw[lane];
    half4 vf = g_pv[lane];

    const char* tabb = reinterpret_cast<const char*>(tab);

    __syncthreads();   // table ready

    for (int s = 0; s < NSTEPS; ++s) {
        int sn = (s < NSTEPS - 1) ? s + 1 : s;
        half4 wfn = g_pw[sn * 64 + lane];
        half4 vfn = g_pv[sn * 64 + lane];

        // Phase 1: h (fp32, C/D layout) -> f16 B-operand, all tiles.
        union { fp16x2 h2[2]; half4 h4; } hb[TILES];
        #pragma unroll
        for (int t = 0; t < TILES; ++t) {
            hb[t].h2[0] = __builtin_amdgcn_cvt_pkrtz(h[t][0], h[t][1]);
            hb[t].h2[1] = __builtin_amdgcn_cvt_pkrtz(h[t][2], h[t][3]);
        }

        // Phase 2: u = W^T @ h^T, all tiles (independent MFMAs).
        floatx4 u[TILES];
        #pragma unroll
        for (int t = 0; t < TILES; ++t) {
            floatx4 zero = {0.f, 0.f, 0.f, 0.f};
            u[t] = __builtin_amdgcn_mfma_f32_16x16x16f16(wf, hb[t].h4, zero, 0, 0, 0);
        }

        // Phase 3: GELU. j=0..2 via LDS table gather (3 VALU + ds_read_u16);
        // j=3 via trans-pipe sigmoid (5 VALU + exp2 + rcp, per-elem indep).
        half4 gb[TILES];
        #pragma unroll
        for (int t = 0; t < TILES; ++t) {
            half4 g4;
            #pragma unroll
            for (int j = 0; j < 3; ++j) {
                int off = ((int)fmaf(u[t][j], 512.0f, 8193.0f)) & 16382;
                g4[j] = *reinterpret_cast<const _Float16*>(tabb + off);
            }
            {
                float xv = u[t][3];
                float z  = xv * fmaf(Kc1, xv * xv, K);
                float e  = __builtin_amdgcn_exp2f(z);
                float rr = __builtin_amdgcn_rcpf(1.0f + e);
                g4[3] = (_Float16)fmaf(-xv, rr, xv);   // u*(1-sigmoid) limits clean
            }
            gb[t] = g4;
        }

        // Phase 4: h += g @ (V/N), all tiles (residual in MFMA C operand).
        #pragma unroll
        for (int t = 0; t < TILES; ++t) {
            h[t] = __builtin_amdgcn_mfma_f32_16x16x16f16(vf, gb[t], h[t], 0, 0, 0);
        }

        wf = wfn; vf = vfn;
    }

    #pragma unroll
    for (int t = 0; t < TILES; ++t) {
        float4 v = make_float4(h[t][0], h[t][1], h[t][2], h[t][3]);
        *reinterpret_cast<float4*>(out + (rowbase + t * 16 + r) * DDIM + 4 * q) = v;
    }
}

extern "C" void kernel_launch(void* const* d_in, const int* in_sizes, int n_in,
                              void* d_out, int out_size, void* d_ws, size_t ws_size,
                              hipStream_t stream) {
    (void)in_sizes; (void)n_in; (void)out_size; (void)d_ws; (void)ws_size;

    const float* x = (const float*)d_in[0];   // [2^21, 16] fp32
    const float* W = (const float*)d_in[1];   // [64, 16, 16] fp32
    const float* V = (const float*)d_in[2];   // [64, 16, 16] fp32
    float* out = (float*)d_out;

    pack_wv<<<16, 256, 0, stream>>>(W, V);

    // 512 rows per block (4 waves x 8 tiles x 16 rows); grid = 2^21/512 = 4096.
    resnet_mfma_kernel<<<(int)(BATCH_N / ROWS_PER_BLOCK), 256, 0, stream>>>(x, out);
}